// Round 25
// baseline (710.263 us; speedup 1.0000x reference)
//
#include <hip/hip_runtime.h>
#include <math.h>

// HeterogeneousGNN fused kernel for MI355X (gfx950) — round 25.
// Base = R24 (630 us). Final barrier-halving attempt with ZERO added
// concurrent register state (R17/R18 died holding 2 GEMM1 accs):
// chunk PAIRS with sequential g0 reuse:
//   g0=GEMM1(c) -> BAR -> store GcA -> g0=GEMM1(c+1) -> store GcB
//   -> BAR -> GEMM2 over K=64 (GcA,GcB)
// Barriers 96 -> 48. Only one g0 live at any time (acc+16, same as base).
// Gc: 2 x [128 o][64-B rows] = 16 KB; LDS = exactly 81920 (R17-proven
// 2-block residency). 64-B stride + XOR (o&3)<<4 -> ~8-way conflicts
// (vs 4-way; conflicts are ~10us total, barriers ~200us -> good trade).

typedef float  f32x4  __attribute__((ext_vector_type(4)));
typedef float  f32x16 __attribute__((ext_vector_type(16)));
typedef short  s16x8  __attribute__((ext_vector_type(8)));
typedef __bf16 bf16x8 __attribute__((ext_vector_type(8)));

#define GOFF 65536   // Gc buffers: A at 65536, B at 73728 (8192 B each)

// LDS-only barrier: commits LDS ops, leaves global loads in flight (R20).
#define LDS_BARRIER() asm volatile("s_waitcnt lgkmcnt(0)\n\ts_barrier" ::: "memory")

__device__ __forceinline__ unsigned short f2bf(float f) {
  __bf16 h = (__bf16)f;
  return __builtin_bit_cast(unsigned short, h);
}
__device__ __forceinline__ float bf2f(unsigned short h) {
  return __builtin_bit_cast(float, (unsigned int)h << 16);
}
__device__ __forceinline__ unsigned short f2bf_rne(float f) {
  unsigned int u = __builtin_bit_cast(unsigned int, f);
  u = (u + 0x7fffu + ((u >> 16) & 1u)) >> 16;
  return (unsigned short)u;
}

// exact-GELU via A&S 7.1.26 erf (max abs err 1.5e-7, << bf16 rounding)
__device__ __forceinline__ float gelu_fast(float x) {
  float z = fabsf(x) * 0.70710678f;
  float t = __builtin_amdgcn_rcpf(1.f + 0.3275911f * z);
  float p = t * (0.254829592f + t * (-0.284496736f + t * (1.421413741f +
            t * (-1.453152027f + t * 1.061405429f))));
  float e = __builtin_expf(-z * z);
  float erfv = 1.f - p * e;
  erfv = (x < 0.f) ? -erfv : erfv;
  return 0.5f * x * (1.f + erfv);
}

// H: [256 v][128 d] bf16; XOR (v&15) -> column b128 reads 2-way (free).
__device__ __forceinline__ int haddr(int v, int d) {
  return v * 256 + ((d * 2) ^ ((v & 15) << 4));
}
// Gc buf: [128 o][32 v] bf16, 64-B rows; XOR (o&3)<<4 spreads the 4 slots.
__device__ __forceinline__ int gaddr(int buf, int o, int vr) {
  return GOFF + buf * 8192 + o * 64 + ((vr * 2) ^ ((o & 3) << 4));
}

#define MFMA32(a, b, c) __builtin_amdgcn_mfma_f32_32x32x16_bf16( \
    __builtin_bit_cast(bf16x8, (a)), __builtin_bit_cast(bf16x8, (b)), (c), 0, 0, 0)

// ---- prep: fragment-ordered A3 / W3 (bf16) — unchanged ----
// A3[h][ut 0..7][vt 0..15][lane][j] = Ac_h[u=ut*32+(lane&31)][v=vt*16+(lane>>5)*8+j]
// W3[hw 0..5][ot 0..3][kt 0..7][lane][j] = W_hw[o=ot*32+(lane&31)][d=kt*16+(lane>>5)*8+j]
__global__ void prep_kernel(const float* __restrict__ alp, const float* __restrict__ aln,
                            const float* __restrict__ wp,  const float* __restrict__ wn,
                            unsigned short* __restrict__ A3, unsigned short* __restrict__ W3) {
  int idx = blockIdx.x * 512 + threadIdx.x;     // 229376 threads total
  if (idx < 131072) {
    int j = idx & 7, lane = (idx >> 3) & 63, vt = (idx >> 9) & 15,
        ut = (idx >> 13) & 7, h = (idx >> 16) & 1;
    int u = ut * 32 + (lane & 31);
    int v = vt * 16 + (lane >> 5) * 8 + j;
    int s = u * 256 + v;
    float ap = 1.f / (1.f + expf(-alp[s]));
    float an = 1.f / (1.f + expf(-aln[s]));
    bool  m  = ap > an;
    float val = h ? (m ? 0.f : -an) : (m ? ap : 0.f);   // neg sign folded
    A3[idx] = f2bf_rne(val);
  } else {
    int k = idx - 131072;                       // 0 .. 98303
    int j = k & 7, lane = (k >> 3) & 63, kt = (k >> 9) & 7,
        ot = (k >> 12) & 3, hw = (k >> 14);     // hw = l*2 + (0=pos,1=neg)
    int o = ot * 32 + (lane & 31);
    int d = kt * 16 + (lane >> 5) * 8 + j;
    const float* src = (hw & 1) ? wn : wp;
    W3[k] = f2bf_rne(src[(hw >> 1) * 16384 + o * 128 + d]);
  }
}

__global__ __launch_bounds__(256, 2) void gnn_kernel(
    const float* __restrict__ X,
    const unsigned short* __restrict__ A3,
    const unsigned short* __restrict__ W3,
    const float* __restrict__ ln_g, const float* __restrict__ ln_b,
    const float* __restrict__ ro_g, const float* __restrict__ ro_b,
    float* __restrict__ out) {
  extern __shared__ char smem[];
  const int tid  = threadIdx.x;
  const int wid  = tid >> 6;        // 0..3
  const int lane = tid & 63;
  const int l31  = lane & 31;
  const int hi   = lane >> 5;
  const int b    = blockIdx.x;

  // ---- stage H = bf16(X[b]) into LDS ----
  {
    const float4* Xb = (const float4*)(X + (size_t)b * 256 * 128);
#pragma unroll 8
    for (int i = 0; i < 32; ++i) {
      int idx = tid + i * 256;                 // 8192 float4 chunks
      int v = idx >> 5, d = (idx & 31) * 4;
      float4 f = Xb[idx];
      ushort4 p;
      p.x = f2bf(f.x); p.y = f2bf(f.y); p.z = f2bf(f.z); p.w = f2bf(f.w);
      *(ushort4*)(smem + haddr(v, d)) = p;
    }
  }
  __syncthreads();

  f32x16 acc[2][4];                  // wave tile: u = wid*64..+64, o = 0..128
  for (int l = 0; l < 3; ++l) {
#pragma unroll
    for (int mt = 0; mt < 2; ++mt)
#pragma unroll
      for (int nt = 0; nt < 4; ++nt)
#pragma unroll
        for (int r = 0; r < 16; ++r) acc[mt][nt][r] = 0.f;

    for (int h = 0; h < 2; ++h) {
      const unsigned short* Wb = W3 + (size_t)(((l * 2 + h) * 4 + wid) * 8) * 512;
      const unsigned short* Ab = A3 + (size_t)((h * 8 + wid * 2) * 16) * 512;

      // hoisted W o-tile fragments, reused by all chunks
      s16x8 wreg[8];
#pragma unroll
      for (int kt = 0; kt < 8; ++kt)
        wreg[kt] = *(const s16x8*)(Wb + (size_t)kt * 512 + lane * 8);

      for (int cp = 0; cp < 4; ++cp) {         // chunk PAIRS (64 nodes)
        const int c = cp * 2;
        // prefetch first-chunk A fragments (kt 0..1 of the pair)
        s16x8 pa[4];
#pragma unroll
        for (int kt = 0; kt < 2; ++kt) {
          pa[kt * 2 + 0] = *(const s16x8*)(Ab + (size_t)(0 * 16 + c * 2 + kt) * 512 + lane * 8);
          pa[kt * 2 + 1] = *(const s16x8*)(Ab + (size_t)(1 * 16 + c * 2 + kt) * 512 + lane * 8);
        }

        // ---- GEMM1(c): one 32x32 tile (g0, the ONLY live G accumulator) ----
        f32x16 g0;
#pragma unroll
        for (int r = 0; r < 16; ++r) g0[r] = 0.f;
        {
          const int v0 = c * 32 + l31;
          __builtin_amdgcn_s_setprio(1);
#pragma unroll
          for (int kt = 0; kt < 8; ++kt) {
            s16x8 ha = *(const s16x8*)(smem + haddr(v0, kt * 16 + hi * 8));
            g0 = MFMA32(ha, wreg[kt], g0);
          }
          __builtin_amdgcn_s_setprio(0);
        }
        LDS_BARRIER();                         // prev pair's GEMM2 reads done
        {
          const int og = wid * 32 + l31;       // store chunk c -> buf A
#pragma unroll
          for (int rq = 0; rq < 4; ++rq) {
            int vr = rq * 8 + hi * 4;
            ushort4 p;
            p.x = f2bf(g0[rq*4+0]); p.y = f2bf(g0[rq*4+1]);
            p.z = f2bf(g0[rq*4+2]); p.w = f2bf(g0[rq*4+3]);
            *(ushort4*)(smem + gaddr(0, og, vr)) = p;
          }
        }
        // ---- GEMM1(c+1): sequential reuse of g0 ----
#pragma unroll
        for (int r = 0; r < 16; ++r) g0[r] = 0.f;
        {
          const int v0 = (c + 1) * 32 + l31;
          __builtin_amdgcn_s_setprio(1);
#pragma unroll
          for (int kt = 0; kt < 8; ++kt) {
            s16x8 ha = *(const s16x8*)(smem + haddr(v0, kt * 16 + hi * 8));
            g0 = MFMA32(ha, wreg[kt], g0);
          }
          __builtin_amdgcn_s_setprio(0);
        }
        {
          const int og = wid * 32 + l31;       // store chunk c+1 -> buf B
#pragma unroll
          for (int rq = 0; rq < 4; ++rq) {
            int vr = rq * 8 + hi * 4;
            ushort4 p;
            p.x = f2bf(g0[rq*4+0]); p.y = f2bf(g0[rq*4+1]);
            p.z = f2bf(g0[rq*4+2]); p.w = f2bf(g0[rq*4+3]);
            *(ushort4*)(smem + gaddr(1, og, vr)) = p;
          }
        }
        LDS_BARRIER();                         // both buffers committed

        // ---- GEMM2: acc += A[u, 64 v of the pair] @ [GcA;GcB]; K=64 ----
        __builtin_amdgcn_s_setprio(1);
#pragma unroll
        for (int kt = 0; kt < 2; ++kt) {       // buf A (chunk c): prefetched A
#pragma unroll
          for (int nt = 0; nt < 4; ++nt) {
            s16x8 bf = *(const s16x8*)(smem + gaddr(0, nt * 32 + l31, kt * 16 + hi * 8));
            acc[0][nt] = MFMA32(pa[kt * 2 + 0], bf, acc[0][nt]);
            acc[1][nt] = MFMA32(pa[kt * 2 + 1], bf, acc[1][nt]);
          }
        }
#pragma unroll
        for (int kt = 0; kt < 2; ++kt) {       // buf B (chunk c+1): inline A
          s16x8 a0 = *(const s16x8*)(Ab + (size_t)(0 * 16 + (c + 1) * 2 + kt) * 512 + lane * 8);
          s16x8 a1 = *(const s16x8*)(Ab + (size_t)(1 * 16 + (c + 1) * 2 + kt) * 512 + lane * 8);
#pragma unroll
          for (int nt = 0; nt < 4; ++nt) {
            s16x8 bf = *(const s16x8*)(smem + gaddr(1, nt * 32 + l31, kt * 16 + hi * 8));
            acc[0][nt] = MFMA32(a0, bf, acc[0][nt]);
            acc[1][nt] = MFMA32(a1, bf, acc[1][nt]);
          }
        }
        __builtin_amdgcn_s_setprio(0);
      } // chunk pairs
    } // halves

    // ---- epilogue: fast exact-GELU + wave-local LayerNorm -> H ----
    {
      float lg[4], lb[4];
#pragma unroll
      for (int nt = 0; nt < 4; ++nt) {
        lg[nt] = ln_g[l * 128 + nt * 32 + l31];
        lb[nt] = ln_b[l * 128 + nt * 32 + l31];
      }
#pragma unroll
      for (int mt = 0; mt < 2; ++mt)
#pragma unroll
        for (int r = 0; r < 16; ++r) {
          float x0 = gelu_fast(acc[mt][0][r]);
          float x1 = gelu_fast(acc[mt][1][r]);
          float x2 = gelu_fast(acc[mt][2][r]);
          float x3 = gelu_fast(acc[mt][3][r]);
          acc[mt][0][r] = x0; acc[mt][1][r] = x1;
          acc[mt][2][r] = x2; acc[mt][3][r] = x3;
          float s1 = x0 + x1 + x2 + x3;
          float s2 = x0 * x0 + x1 * x1 + x2 * x2 + x3 * x3;
#pragma unroll
          for (int m = 1; m < 32; m <<= 1) {   // full row (128 cols) reduce
            s1 += __shfl_xor(s1, m);
            s2 += __shfl_xor(s2, m);
          }
          float mu  = s1 * (1.f / 128.f);
          float var = s2 * (1.f / 128.f) - mu * mu;
          float rs  = rsqrtf(var + 1e-5f);
          int u = wid * 64 + mt * 32 + (r & 3) + 8 * ((r >> 2) & 3) + 4 * hi;
#pragma unroll
          for (int nt = 0; nt < 4; ++nt) {
            float y = (acc[mt][nt][r] - mu) * rs * lg[nt] + lb[nt];
            *(unsigned short*)(smem + haddr(u, nt * 32 + l31)) = f2bf(y);
          }
        }
    }
    __syncthreads();                           // H' ready for next layer
  } // layers

  // ---- readout: mean over nodes + final LN ----
  {
    int d   = tid & 127;
    int grp = tid >> 7;                        // 0..1, 128 rows each
    float s = 0.f;
    for (int v = grp * 128; v < grp * 128 + 128; ++v)
      s += bf2f(*(const unsigned short*)(smem + haddr(v, d)));
    float* red = (float*)(smem + GOFF);        // Gc region is dead now
    red[grp * 128 + d] = s;
    __syncthreads();
    if (tid < 128) {
      red[256 + tid] = (red[tid] + red[128 + tid]) * (1.f / 256.f);
    }
    __syncthreads();
    if (tid < 64) {
      float a  = red[256 + tid];
      float b2 = red[256 + 64 + tid];
      float s1 = a + b2, s2 = a * a + b2 * b2;
#pragma unroll
      for (int m = 1; m < 64; m <<= 1) {
        s1 += __shfl_xor(s1, m);
        s2 += __shfl_xor(s2, m);
      }
      float mu  = s1 * (1.f / 128.f);
      float var = s2 * (1.f / 128.f) - mu * mu;
      float rs  = rsqrtf(var + 1e-5f);
      out[(size_t)b * 128 + tid]      = (a  - mu) * rs * ro_g[tid]      + ro_b[tid];
      out[(size_t)b * 128 + 64 + tid] = (b2 - mu) * rs * ro_g[64 + tid] + ro_b[64 + tid];
    }
  }
}

extern "C" void kernel_launch(void* const* d_in, const int* in_sizes, int n_in,
                              void* d_out, int out_size, void* d_ws, size_t ws_size,
                              hipStream_t stream) {
  const float* X   = (const float*)d_in[0];
  const float* alp = (const float*)d_in[1];
  const float* aln = (const float*)d_in[2];
  const float* wp  = (const float*)d_in[3];
  const float* wn  = (const float*)d_in[4];
  const float* lng = (const float*)d_in[5];
  const float* lnb = (const float*)d_in[6];
  const float* rog = (const float*)d_in[7];
  const float* rob = (const float*)d_in[8];
  float* out = (float*)d_out;

  unsigned short* A3 = (unsigned short*)d_ws;          // 131072 bf16 = 256 KB
  unsigned short* W3 = A3 + 131072;                    //  98304 bf16 = 192 KB

  (void)hipFuncSetAttribute(reinterpret_cast<const void*>(gnn_kernel),
                            hipFuncAttributeMaxDynamicSharedMemorySize, 81920);

  prep_kernel<<<448, 512, 0, stream>>>(alp, aln, wp, wn, A3, W3);
  gnn_kernel<<<2048, 256, 81920, stream>>>(X, A3, W3, lng, lnb, rog, rob, out);
}

// Round 26
// 659.089 us; speedup vs baseline: 1.0776x; 1.0776x over previous
//
#include <hip/hip_runtime.h>
#include <math.h>

// HeterogeneousGNN fused kernel for MI355X (gfx950) — round 26.
// Base = R24 (630 us best). R25 post-mortem: its 64-B-stride XOR used the
// WRONG bits ((o&3)<<4 -> only 4 of 8 bank groups -> 8-way, conflicts x9);
// the barrier-halving idea was never actually tested. R26 tests it cleanly:
// double-buffered Gc, ONE barrier per chunk (store to buf[c&1] right after
// GEMM1 -- WAR-safe: buf's last readers were chunk c-2, separated by chunk
// c-1's barrier). Barriers 96 -> 48, ZERO register delta vs R24.
// Gc buf: [128 o][32 v] bf16, 64-B rows, XOR ((o>>1)&3)<<4 ->
// start bank = 16(o&1)+4((o>>1)&3) covers all 8 groups -> 4-way b128 floor.
// LDS = 65536 + 2*8192 = 81920 exactly (2-block residency proven R17/R25).

typedef float  f32x4  __attribute__((ext_vector_type(4)));
typedef float  f32x16 __attribute__((ext_vector_type(16)));
typedef short  s16x8  __attribute__((ext_vector_type(8)));
typedef __bf16 bf16x8 __attribute__((ext_vector_type(8)));

#define GOFF 65536   // Gc buffers: A at 65536, B at 73728 (8192 B each)

// LDS-only barrier: commits LDS ops, leaves global loads in flight (R20).
#define LDS_BARRIER() asm volatile("s_waitcnt lgkmcnt(0)\n\ts_barrier" ::: "memory")

__device__ __forceinline__ unsigned short f2bf(float f) {
  __bf16 h = (__bf16)f;
  return __builtin_bit_cast(unsigned short, h);
}
__device__ __forceinline__ float bf2f(unsigned short h) {
  return __builtin_bit_cast(float, (unsigned int)h << 16);
}
__device__ __forceinline__ unsigned short f2bf_rne(float f) {
  unsigned int u = __builtin_bit_cast(unsigned int, f);
  u = (u + 0x7fffu + ((u >> 16) & 1u)) >> 16;
  return (unsigned short)u;
}

// exact-GELU via A&S 7.1.26 erf (max abs err 1.5e-7, << bf16 rounding)
__device__ __forceinline__ float gelu_fast(float x) {
  float z = fabsf(x) * 0.70710678f;
  float t = __builtin_amdgcn_rcpf(1.f + 0.3275911f * z);
  float p = t * (0.254829592f + t * (-0.284496736f + t * (1.421413741f +
            t * (-1.453152027f + t * 1.061405429f))));
  float e = __builtin_expf(-z * z);
  float erfv = 1.f - p * e;
  erfv = (x < 0.f) ? -erfv : erfv;
  return 0.5f * x * (1.f + erfv);
}

// H: [256 v][128 d] bf16; XOR (v&15) -> column b128 reads 2-way (free).
__device__ __forceinline__ int haddr(int v, int d) {
  return v * 256 + ((d * 2) ^ ((v & 15) << 4));
}
// Gc buf: [128 o][32 v] bf16, 64-B rows; XOR ((o>>1)&3)<<4 (see header).
__device__ __forceinline__ int gaddr(int buf, int o, int vr) {
  return GOFF + buf * 8192 + o * 64 + ((vr * 2) ^ (((o >> 1) & 3) << 4));
}

#define MFMA32(a, b, c) __builtin_amdgcn_mfma_f32_32x32x16_bf16( \
    __builtin_bit_cast(bf16x8, (a)), __builtin_bit_cast(bf16x8, (b)), (c), 0, 0, 0)

// ---- prep: fragment-ordered A3 / W3 (bf16) — unchanged ----
// A3[h][ut 0..7][vt 0..15][lane][j] = Ac_h[u=ut*32+(lane&31)][v=vt*16+(lane>>5)*8+j]
// W3[hw 0..5][ot 0..3][kt 0..7][lane][j] = W_hw[o=ot*32+(lane&31)][d=kt*16+(lane>>5)*8+j]
__global__ void prep_kernel(const float* __restrict__ alp, const float* __restrict__ aln,
                            const float* __restrict__ wp,  const float* __restrict__ wn,
                            unsigned short* __restrict__ A3, unsigned short* __restrict__ W3) {
  int idx = blockIdx.x * 512 + threadIdx.x;     // 229376 threads total
  if (idx < 131072) {
    int j = idx & 7, lane = (idx >> 3) & 63, vt = (idx >> 9) & 15,
        ut = (idx >> 13) & 7, h = (idx >> 16) & 1;
    int u = ut * 32 + (lane & 31);
    int v = vt * 16 + (lane >> 5) * 8 + j;
    int s = u * 256 + v;
    float ap = 1.f / (1.f + expf(-alp[s]));
    float an = 1.f / (1.f + expf(-aln[s]));
    bool  m  = ap > an;
    float val = h ? (m ? 0.f : -an) : (m ? ap : 0.f);   // neg sign folded
    A3[idx] = f2bf_rne(val);
  } else {
    int k = idx - 131072;                       // 0 .. 98303
    int j = k & 7, lane = (k >> 3) & 63, kt = (k >> 9) & 7,
        ot = (k >> 12) & 3, hw = (k >> 14);     // hw = l*2 + (0=pos,1=neg)
    int o = ot * 32 + (lane & 31);
    int d = kt * 16 + (lane >> 5) * 8 + j;
    const float* src = (hw & 1) ? wn : wp;
    W3[k] = f2bf_rne(src[(hw >> 1) * 16384 + o * 128 + d]);
  }
}

__global__ __launch_bounds__(256, 2) void gnn_kernel(
    const float* __restrict__ X,
    const unsigned short* __restrict__ A3,
    const unsigned short* __restrict__ W3,
    const float* __restrict__ ln_g, const float* __restrict__ ln_b,
    const float* __restrict__ ro_g, const float* __restrict__ ro_b,
    float* __restrict__ out) {
  extern __shared__ char smem[];
  const int tid  = threadIdx.x;
  const int wid  = tid >> 6;        // 0..3
  const int lane = tid & 63;
  const int l31  = lane & 31;
  const int hi   = lane >> 5;
  const int b    = blockIdx.x;

  // ---- stage H = bf16(X[b]) into LDS ----
  {
    const float4* Xb = (const float4*)(X + (size_t)b * 256 * 128);
#pragma unroll 8
    for (int i = 0; i < 32; ++i) {
      int idx = tid + i * 256;                 // 8192 float4 chunks
      int v = idx >> 5, d = (idx & 31) * 4;
      float4 f = Xb[idx];
      ushort4 p;
      p.x = f2bf(f.x); p.y = f2bf(f.y); p.z = f2bf(f.z); p.w = f2bf(f.w);
      *(ushort4*)(smem + haddr(v, d)) = p;
    }
  }
  __syncthreads();

  f32x16 acc[2][4];                  // wave tile: u = wid*64..+64, o = 0..128
  for (int l = 0; l < 3; ++l) {
#pragma unroll
    for (int mt = 0; mt < 2; ++mt)
#pragma unroll
      for (int nt = 0; nt < 4; ++nt)
#pragma unroll
        for (int r = 0; r < 16; ++r) acc[mt][nt][r] = 0.f;

    for (int h = 0; h < 2; ++h) {
      const unsigned short* Wb = W3 + (size_t)(((l * 2 + h) * 4 + wid) * 8) * 512;
      const unsigned short* Ab = A3 + (size_t)((h * 8 + wid * 2) * 16) * 512;

      // hoisted W o-tile fragments, reused by all 8 chunks
      s16x8 wreg[8];
#pragma unroll
      for (int kt = 0; kt < 8; ++kt)
        wreg[kt] = *(const s16x8*)(Wb + (size_t)kt * 512 + lane * 8);

      for (int c = 0; c < 8; ++c) {            // v-chunks of 32 nodes
        const int buf = c & 1;                 // Gc double-buffer parity
        // prefetch this chunk's A fragments (consumed after the barrier)
        s16x8 pa[4];
#pragma unroll
        for (int kt = 0; kt < 2; ++kt) {
          pa[kt * 2 + 0] = *(const s16x8*)(Ab + (size_t)(0 * 16 + c * 2 + kt) * 512 + lane * 8);
          pa[kt * 2 + 1] = *(const s16x8*)(Ab + (size_t)(1 * 16 + c * 2 + kt) * 512 + lane * 8);
        }

        // ---- GEMM1: Gc[32v][128o] = H[c] @ W^T; one 32x32 tile per wave ----
        f32x16 g0;
#pragma unroll
        for (int r = 0; r < 16; ++r) g0[r] = 0.f;
        const int v0 = c * 32 + l31;
        __builtin_amdgcn_s_setprio(1);
#pragma unroll
        for (int kt = 0; kt < 8; ++kt) {       // K = d = 128
          s16x8 ha = *(const s16x8*)(smem + haddr(v0, kt * 16 + hi * 8));
          g0 = MFMA32(ha, wreg[kt], g0);
        }
        __builtin_amdgcn_s_setprio(0);
        // store straight into buf[c&1]: WAR-safe (last readers of this buf
        // were chunk c-2, separated by chunk c-1's barrier)
        {
          const int og = wid * 32 + l31;       // C/D col = lane&31
#pragma unroll
          for (int rq = 0; rq < 4; ++rq) {     // rows v = (r&3)+8*(r>>2)+4*hi
            int vr = rq * 8 + hi * 4;
            ushort4 p;
            p.x = f2bf(g0[rq*4+0]); p.y = f2bf(g0[rq*4+1]);
            p.z = f2bf(g0[rq*4+2]); p.w = f2bf(g0[rq*4+3]);
            *(ushort4*)(smem + gaddr(buf, og, vr)) = p;
          }
        }
        LDS_BARRIER();                         // single barrier per chunk

        // ---- GEMM2: acc += Ac_h[u, 32c..] @ Gc[buf]; 64u x 128o per wave ----
        __builtin_amdgcn_s_setprio(1);
#pragma unroll
        for (int kt = 0; kt < 2; ++kt) {       // K = v-chunk = 32
#pragma unroll
          for (int nt = 0; nt < 4; ++nt) {
            s16x8 bf = *(const s16x8*)(smem + gaddr(buf, nt * 32 + l31, kt * 16 + hi * 8));
            acc[0][nt] = MFMA32(pa[kt * 2 + 0], bf, acc[0][nt]);
            acc[1][nt] = MFMA32(pa[kt * 2 + 1], bf, acc[1][nt]);
          }
        }
        __builtin_amdgcn_s_setprio(0);
      } // chunks
    } // halves

    // ---- epilogue: fast exact-GELU + wave-local LayerNorm -> H ----
    {
      float lg[4], lb[4];
#pragma unroll
      for (int nt = 0; nt < 4; ++nt) {
        lg[nt] = ln_g[l * 128 + nt * 32 + l31];
        lb[nt] = ln_b[l * 128 + nt * 32 + l31];
      }
#pragma unroll
      for (int mt = 0; mt < 2; ++mt)
#pragma unroll
        for (int r = 0; r < 16; ++r) {
          float x0 = gelu_fast(acc[mt][0][r]);
          float x1 = gelu_fast(acc[mt][1][r]);
          float x2 = gelu_fast(acc[mt][2][r]);
          float x3 = gelu_fast(acc[mt][3][r]);
          acc[mt][0][r] = x0; acc[mt][1][r] = x1;
          acc[mt][2][r] = x2; acc[mt][3][r] = x3;
          float s1 = x0 + x1 + x2 + x3;
          float s2 = x0 * x0 + x1 * x1 + x2 * x2 + x3 * x3;
#pragma unroll
          for (int m = 1; m < 32; m <<= 1) {   // full row (128 cols) reduce
            s1 += __shfl_xor(s1, m);
            s2 += __shfl_xor(s2, m);
          }
          float mu  = s1 * (1.f / 128.f);
          float var = s2 * (1.f / 128.f) - mu * mu;
          float rs  = rsqrtf(var + 1e-5f);
          int u = wid * 64 + mt * 32 + (r & 3) + 8 * ((r >> 2) & 3) + 4 * hi;
#pragma unroll
          for (int nt = 0; nt < 4; ++nt) {
            float y = (acc[mt][nt][r] - mu) * rs * lg[nt] + lb[nt];
            *(unsigned short*)(smem + haddr(u, nt * 32 + l31)) = f2bf(y);
          }
        }
    }
    __syncthreads();                           // H' ready for next layer
  } // layers

  // ---- readout: mean over nodes + final LN ----
  {
    int d   = tid & 127;
    int grp = tid >> 7;                        // 0..1, 128 rows each
    float s = 0.f;
    for (int v = grp * 128; v < grp * 128 + 128; ++v)
      s += bf2f(*(const unsigned short*)(smem + haddr(v, d)));
    float* red = (float*)(smem + GOFF);        // Gc region is dead now
    red[grp * 128 + d] = s;
    __syncthreads();
    if (tid < 128) {
      red[256 + tid] = (red[tid] + red[128 + tid]) * (1.f / 256.f);
    }
    __syncthreads();
    if (tid < 64) {
      float a  = red[256 + tid];
      float b2 = red[256 + 64 + tid];
      float s1 = a + b2, s2 = a * a + b2 * b2;
#pragma unroll
      for (int m = 1; m < 64; m <<= 1) {
        s1 += __shfl_xor(s1, m);
        s2 += __shfl_xor(s2, m);
      }
      float mu  = s1 * (1.f / 128.f);
      float var = s2 * (1.f / 128.f) - mu * mu;
      float rs  = rsqrtf(var + 1e-5f);
      out[(size_t)b * 128 + tid]      = (a  - mu) * rs * ro_g[tid]      + ro_b[tid];
      out[(size_t)b * 128 + 64 + tid] = (b2 - mu) * rs * ro_g[64 + tid] + ro_b[64 + tid];
    }
  }
}

extern "C" void kernel_launch(void* const* d_in, const int* in_sizes, int n_in,
                              void* d_out, int out_size, void* d_ws, size_t ws_size,
                              hipStream_t stream) {
  const float* X   = (const float*)d_in[0];
  const float* alp = (const float*)d_in[1];
  const float* aln = (const float*)d_in[2];
  const float* wp  = (const float*)d_in[3];
  const float* wn  = (const float*)d_in[4];
  const float* lng = (const float*)d_in[5];
  const float* lnb = (const float*)d_in[6];
  const float* rog = (const float*)d_in[7];
  const float* rob = (const float*)d_in[8];
  float* out = (float*)d_out;

  unsigned short* A3 = (unsigned short*)d_ws;          // 131072 bf16 = 256 KB
  unsigned short* W3 = A3 + 131072;                    //  98304 bf16 = 192 KB

  (void)hipFuncSetAttribute(reinterpret_cast<const void*>(gnn_kernel),
                            hipFuncAttributeMaxDynamicSharedMemorySize, 81920);

  prep_kernel<<<448, 512, 0, stream>>>(alp, aln, wp, wn, A3, W3);
  gnn_kernel<<<2048, 256, 81920, stream>>>(X, A3, W3, lng, lnb, rog, rob, out);
}

// Round 27
// 630.530 us; speedup vs baseline: 1.1265x; 1.0453x over previous
//
#include <hip/hip_runtime.h>
#include <math.h>

// HeterogeneousGNN fused kernel for MI355X (gfx950) — FINAL (= round 24 best,
// 630 us, 2.3x faster than the first passing version's 1473 us).
// Design: one 256-thread WG (4 waves) per batch element; H[b] (256x128 bf16,
// XOR-swizzled) resident in LDS across all 3 layers. Per (layer, half), per
// 32-node chunk: GEMM1 (32x32 MFMA tile/wave, W frags hoisted in regs) ->
// Gc^T in LDS (80-B row stride: start-bank 5*o mod 8 covers all groups,
// 4-way b128 floor) -> GEMM2 (64u x 128o/wave, acc[2][4] f32x16 in AGPRs,
// A-frags prefetched before the barriers). Epilogue: A&S-7.1.26 exact GELU
// + wave-local shuffle LayerNorm. LDS-only barriers (lgkmcnt drain, globals
// stay in flight) + s_setprio around MFMA clusters.
// Register box (measured over 26 rounds): 256-thr/(256,2) -> 128 arch + 128
// AGPR; every structural attempt to cut barriers/raise occupancy (wave-
// private Gc, fused halves, 64-node chunks, chunk pairs, dbuf) lost more to
// spill or bank conflicts than it gained. This config is the measured optimum.

typedef float  f32x4  __attribute__((ext_vector_type(4)));
typedef float  f32x16 __attribute__((ext_vector_type(16)));
typedef short  s16x8  __attribute__((ext_vector_type(8)));
typedef __bf16 bf16x8 __attribute__((ext_vector_type(8)));

#define GOFF 65536   // Gc region byte offset (10240 B)

// LDS-only barrier: commits LDS ops, leaves global loads in flight.
#define LDS_BARRIER() asm volatile("s_waitcnt lgkmcnt(0)\n\ts_barrier" ::: "memory")

__device__ __forceinline__ unsigned short f2bf(float f) {
  __bf16 h = (__bf16)f;
  return __builtin_bit_cast(unsigned short, h);
}
__device__ __forceinline__ float bf2f(unsigned short h) {
  return __builtin_bit_cast(float, (unsigned int)h << 16);
}
__device__ __forceinline__ unsigned short f2bf_rne(float f) {
  unsigned int u = __builtin_bit_cast(unsigned int, f);
  u = (u + 0x7fffu + ((u >> 16) & 1u)) >> 16;
  return (unsigned short)u;
}

// exact-GELU via A&S 7.1.26 erf (max abs err 1.5e-7, << bf16 rounding)
__device__ __forceinline__ float gelu_fast(float x) {
  float z = fabsf(x) * 0.70710678f;
  float t = __builtin_amdgcn_rcpf(1.f + 0.3275911f * z);
  float p = t * (0.254829592f + t * (-0.284496736f + t * (1.421413741f +
            t * (-1.453152027f + t * 1.061405429f))));
  float e = __builtin_expf(-z * z);
  float erfv = 1.f - p * e;
  erfv = (x < 0.f) ? -erfv : erfv;
  return 0.5f * x * (1.f + erfv);
}

// H: [256 v][128 d] bf16; XOR (v&15) -> column b128 reads 2-way (free).
__device__ __forceinline__ int haddr(int v, int d) {
  return v * 256 + ((d * 2) ^ ((v & 15) << 4));
}
// Gc^T: [128 o][32 v] bf16, 80-B row stride; slot(o)=5*o mod 8 -> 4-way floor.
__device__ __forceinline__ int gaddr(int o, int vr) {
  return GOFF + o * 80 + vr * 2;
}

#define MFMA32(a, b, c) __builtin_amdgcn_mfma_f32_32x32x16_bf16( \
    __builtin_bit_cast(bf16x8, (a)), __builtin_bit_cast(bf16x8, (b)), (c), 0, 0, 0)

// ---- prep: fragment-ordered A3 / W3 (bf16) ----
// A3[h][ut 0..7][vt 0..15][lane][j] = Ac_h[u=ut*32+(lane&31)][v=vt*16+(lane>>5)*8+j]
// W3[hw 0..5][ot 0..3][kt 0..7][lane][j] = W_hw[o=ot*32+(lane&31)][d=kt*16+(lane>>5)*8+j]
__global__ void prep_kernel(const float* __restrict__ alp, const float* __restrict__ aln,
                            const float* __restrict__ wp,  const float* __restrict__ wn,
                            unsigned short* __restrict__ A3, unsigned short* __restrict__ W3) {
  int idx = blockIdx.x * 512 + threadIdx.x;     // 229376 threads total
  if (idx < 131072) {
    int j = idx & 7, lane = (idx >> 3) & 63, vt = (idx >> 9) & 15,
        ut = (idx >> 13) & 7, h = (idx >> 16) & 1;
    int u = ut * 32 + (lane & 31);
    int v = vt * 16 + (lane >> 5) * 8 + j;
    int s = u * 256 + v;
    float ap = 1.f / (1.f + expf(-alp[s]));
    float an = 1.f / (1.f + expf(-aln[s]));
    bool  m  = ap > an;
    float val = h ? (m ? 0.f : -an) : (m ? ap : 0.f);   // neg sign folded
    A3[idx] = f2bf_rne(val);
  } else {
    int k = idx - 131072;                       // 0 .. 98303
    int j = k & 7, lane = (k >> 3) & 63, kt = (k >> 9) & 7,
        ot = (k >> 12) & 3, hw = (k >> 14);     // hw = l*2 + (0=pos,1=neg)
    int o = ot * 32 + (lane & 31);
    int d = kt * 16 + (lane >> 5) * 8 + j;
    const float* src = (hw & 1) ? wn : wp;
    W3[k] = f2bf_rne(src[(hw >> 1) * 16384 + o * 128 + d]);
  }
}

__global__ __launch_bounds__(256, 2) void gnn_kernel(
    const float* __restrict__ X,
    const unsigned short* __restrict__ A3,
    const unsigned short* __restrict__ W3,
    const float* __restrict__ ln_g, const float* __restrict__ ln_b,
    const float* __restrict__ ro_g, const float* __restrict__ ro_b,
    float* __restrict__ out) {
  extern __shared__ char smem[];
  const int tid  = threadIdx.x;
  const int wid  = tid >> 6;        // 0..3
  const int lane = tid & 63;
  const int l31  = lane & 31;
  const int hi   = lane >> 5;
  const int b    = blockIdx.x;

  // ---- stage H = bf16(X[b]) into LDS ----
  {
    const float4* Xb = (const float4*)(X + (size_t)b * 256 * 128);
#pragma unroll 8
    for (int i = 0; i < 32; ++i) {
      int idx = tid + i * 256;                 // 8192 float4 chunks
      int v = idx >> 5, d = (idx & 31) * 4;
      float4 f = Xb[idx];
      ushort4 p;
      p.x = f2bf(f.x); p.y = f2bf(f.y); p.z = f2bf(f.z); p.w = f2bf(f.w);
      *(ushort4*)(smem + haddr(v, d)) = p;
    }
  }
  __syncthreads();

  f32x16 acc[2][4];                  // wave tile: u = wid*64..+64, o = 0..128
  for (int l = 0; l < 3; ++l) {
#pragma unroll
    for (int mt = 0; mt < 2; ++mt)
#pragma unroll
      for (int nt = 0; nt < 4; ++nt)
#pragma unroll
        for (int r = 0; r < 16; ++r) acc[mt][nt][r] = 0.f;

    for (int h = 0; h < 2; ++h) {
      const unsigned short* Wb = W3 + (size_t)(((l * 2 + h) * 4 + wid) * 8) * 512;
      const unsigned short* Ab = A3 + (size_t)((h * 8 + wid * 2) * 16) * 512;

      // hoisted W o-tile fragments, reused by all 8 chunks
      s16x8 wreg[8];
#pragma unroll
      for (int kt = 0; kt < 8; ++kt)
        wreg[kt] = *(const s16x8*)(Wb + (size_t)kt * 512 + lane * 8);

      for (int c = 0; c < 8; ++c) {            // v-chunks of 32 nodes
        // prefetch this chunk's A fragments (consumed after the barriers)
        s16x8 pa[4];
#pragma unroll
        for (int kt = 0; kt < 2; ++kt) {
          pa[kt * 2 + 0] = *(const s16x8*)(Ab + (size_t)(0 * 16 + c * 2 + kt) * 512 + lane * 8);
          pa[kt * 2 + 1] = *(const s16x8*)(Ab + (size_t)(1 * 16 + c * 2 + kt) * 512 + lane * 8);
        }

        // ---- GEMM1: Gc[32v][128o] = H[c] @ W^T; one 32x32 tile per wave ----
        f32x16 g0;
#pragma unroll
        for (int r = 0; r < 16; ++r) g0[r] = 0.f;
        const int v0 = c * 32 + l31;
        __builtin_amdgcn_s_setprio(1);
#pragma unroll
        for (int kt = 0; kt < 8; ++kt) {       // K = d = 128
          s16x8 ha = *(const s16x8*)(smem + haddr(v0, kt * 16 + hi * 8));
          g0 = MFMA32(ha, wreg[kt], g0);
        }
        __builtin_amdgcn_s_setprio(0);
        LDS_BARRIER();                         // prev chunk's GEMM2 reads done
        {
          const int og = wid * 32 + l31;       // C/D col = lane&31
#pragma unroll
          for (int rq = 0; rq < 4; ++rq) {     // rows v = (r&3)+8*(r>>2)+4*hi
            int vr = rq * 8 + hi * 4;
            ushort4 p;
            p.x = f2bf(g0[rq*4+0]); p.y = f2bf(g0[rq*4+1]);
            p.z = f2bf(g0[rq*4+2]); p.w = f2bf(g0[rq*4+3]);
            *(ushort4*)(smem + gaddr(og, vr)) = p;
          }
        }
        LDS_BARRIER();                         // Gc ready (writes committed)

        // ---- GEMM2: acc += Ac_h[u, 32c..] @ Gc; 64u x 128o per wave ----
        __builtin_amdgcn_s_setprio(1);
#pragma unroll
        for (int kt = 0; kt < 2; ++kt) {       // K = v-chunk = 32
#pragma unroll
          for (int nt = 0; nt < 4; ++nt) {
            s16x8 bf = *(const s16x8*)(smem + gaddr(nt * 32 + l31, kt * 16 + hi * 8));
            acc[0][nt] = MFMA32(pa[kt * 2 + 0], bf, acc[0][nt]);
            acc[1][nt] = MFMA32(pa[kt * 2 + 1], bf, acc[1][nt]);
          }
        }
        __builtin_amdgcn_s_setprio(0);
      } // chunks
    } // halves

    // ---- epilogue: fast exact-GELU + wave-local LayerNorm -> H ----
    {
      float lg[4], lb[4];
#pragma unroll
      for (int nt = 0; nt < 4; ++nt) {
        lg[nt] = ln_g[l * 128 + nt * 32 + l31];
        lb[nt] = ln_b[l * 128 + nt * 32 + l31];
      }
#pragma unroll
      for (int mt = 0; mt < 2; ++mt)
#pragma unroll
        for (int r = 0; r < 16; ++r) {
          float x0 = gelu_fast(acc[mt][0][r]);
          float x1 = gelu_fast(acc[mt][1][r]);
          float x2 = gelu_fast(acc[mt][2][r]);
          float x3 = gelu_fast(acc[mt][3][r]);
          acc[mt][0][r] = x0; acc[mt][1][r] = x1;
          acc[mt][2][r] = x2; acc[mt][3][r] = x3;
          float s1 = x0 + x1 + x2 + x3;
          float s2 = x0 * x0 + x1 * x1 + x2 * x2 + x3 * x3;
#pragma unroll
          for (int m = 1; m < 32; m <<= 1) {   // full row (128 cols) reduce
            s1 += __shfl_xor(s1, m);
            s2 += __shfl_xor(s2, m);
          }
          float mu  = s1 * (1.f / 128.f);
          float var = s2 * (1.f / 128.f) - mu * mu;
          float rs  = rsqrtf(var + 1e-5f);
          int u = wid * 64 + mt * 32 + (r & 3) + 8 * ((r >> 2) & 3) + 4 * hi;
#pragma unroll
          for (int nt = 0; nt < 4; ++nt) {
            float y = (acc[mt][nt][r] - mu) * rs * lg[nt] + lb[nt];
            *(unsigned short*)(smem + haddr(u, nt * 32 + l31)) = f2bf(y);
          }
        }
    }
    __syncthreads();                           // H' ready for next layer
  } // layers

  // ---- readout: mean over nodes + final LN ----
  {
    int d   = tid & 127;
    int grp = tid >> 7;                        // 0..1, 128 rows each
    float s = 0.f;
    for (int v = grp * 128; v < grp * 128 + 128; ++v)
      s += bf2f(*(const unsigned short*)(smem + haddr(v, d)));
    float* red = (float*)(smem + GOFF);        // Gc region is dead now
    red[grp * 128 + d] = s;
    __syncthreads();
    if (tid < 128) {
      red[256 + tid] = (red[tid] + red[128 + tid]) * (1.f / 256.f);
    }
    __syncthreads();
    if (tid < 64) {
      float a  = red[256 + tid];
      float b2 = red[256 + 64 + tid];
      float s1 = a + b2, s2 = a * a + b2 * b2;
#pragma unroll
      for (int m = 1; m < 64; m <<= 1) {
        s1 += __shfl_xor(s1, m);
        s2 += __shfl_xor(s2, m);
      }
      float mu  = s1 * (1.f / 128.f);
      float var = s2 * (1.f / 128.f) - mu * mu;
      float rs  = rsqrtf(var + 1e-5f);
      out[(size_t)b * 128 + tid]      = (a  - mu) * rs * ro_g[tid]      + ro_b[tid];
      out[(size_t)b * 128 + 64 + tid] = (b2 - mu) * rs * ro_g[64 + tid] + ro_b[64 + tid];
    }
  }
}

extern "C" void kernel_launch(void* const* d_in, const int* in_sizes, int n_in,
                              void* d_out, int out_size, void* d_ws, size_t ws_size,
                              hipStream_t stream) {
  const float* X   = (const float*)d_in[0];
  const float* alp = (const float*)d_in[1];
  const float* aln = (const float*)d_in[2];
  const float* wp  = (const float*)d_in[3];
  const float* wn  = (const float*)d_in[4];
  const float* lng = (const float*)d_in[5];
  const float* lnb = (const float*)d_in[6];
  const float* rog = (const float*)d_in[7];
  const float* rob = (const float*)d_in[8];
  float* out = (float*)d_out;

  unsigned short* A3 = (unsigned short*)d_ws;          // 131072 bf16 = 256 KB
  unsigned short* W3 = A3 + 131072;                    //  98304 bf16 = 192 KB

  (void)hipFuncSetAttribute(reinterpret_cast<const void*>(gnn_kernel),
                            hipFuncAttributeMaxDynamicSharedMemorySize, 75776);

  prep_kernel<<<448, 512, 0, stream>>>(alp, aln, wp, wn, A3, W3);
  gnn_kernel<<<2048, 256, 75776, stream>>>(X, A3, W3, lng, lnb, rog, rob, out);
}